// Round 2
// baseline (239.999 us; speedup 1.0000x reference)
//
#include <hip/hip_runtime.h>

#define NJ 19
#define ROOT_SCALE 200.0f
#define BLOCK 256

struct Xform { float r[9]; float t[3]; };

__device__ __forceinline__ void quat_rt(float w, float x, float y, float z,
                                        float tx, float ty, float tz, Xform& o) {
    float ts = 2.0f / (w*w + x*x + y*y + z*z);
    o.r[0] = 1.0f - ts*(y*y + z*z); o.r[1] = ts*(x*y - z*w);        o.r[2] = ts*(x*z + y*w);
    o.r[3] = ts*(x*y + z*w);        o.r[4] = 1.0f - ts*(x*x + z*z); o.r[5] = ts*(y*z - x*w);
    o.r[6] = ts*(x*z - y*w);        o.r[7] = ts*(y*z + x*w);        o.r[8] = 1.0f - ts*(x*x + y*y);
    o.t[0] = o.r[0]*tx + o.r[1]*ty + o.r[2]*tz;
    o.t[1] = o.r[3]*tx + o.r[4]*ty + o.r[5]*tz;
    o.t[2] = o.r[6]*tx + o.r[7]*ty + o.r[8]*tz;
}

// o = p ∘ l  (rigid compose): o.r = p.r*l.r ; o.t = p.r*l.t + p.t
__device__ __forceinline__ void compose(const Xform& p, const Xform& l, Xform& o) {
#pragma unroll
    for (int i = 0; i < 3; ++i) {
        o.r[i*3+0] = p.r[i*3+0]*l.r[0] + p.r[i*3+1]*l.r[3] + p.r[i*3+2]*l.r[6];
        o.r[i*3+1] = p.r[i*3+0]*l.r[1] + p.r[i*3+1]*l.r[4] + p.r[i*3+2]*l.r[7];
        o.r[i*3+2] = p.r[i*3+0]*l.r[2] + p.r[i*3+1]*l.r[5] + p.r[i*3+2]*l.r[8];
        o.t[i]     = p.r[i*3+0]*l.t[0] + p.r[i*3+1]*l.t[1] + p.r[i*3+2]*l.t[2] + p.t[i];
    }
}

// No LDS, no barriers: each thread owns one contiguous 304 B row.
// All 19 float4 loads are issued up front (one ~19.5 KB burst per wave in
// flight) so HBM latency is covered by MLP instead of occupancy. Each 128 B
// line is fully consumed by the same wave's burst, so L1/MSHRs absorb the
// within-line redundancy and HBM FETCH stays exact.
__global__ __launch_bounds__(BLOCK, 3) void fk_kernel(
    const float* __restrict__ root, const float* __restrict__ joint,
    const float* __restrict__ offs, float* __restrict__ out, int batch)
{
    const int b = blockIdx.x * BLOCK + threadIdx.x;
    if (b >= batch) return;

    const float4* __restrict__ jq = (const float4*)joint;   // rows are 16B-aligned (304 B)
    float4* __restrict__ o4 = (float4*)out;
    const long long base = (long long)b * NJ;

    // ---- burst-load the whole row into registers (static indexing -> VGPRs) ----
    float4 q[NJ];
#pragma unroll
    for (int j = 0; j < NJ; ++j) q[j] = jq[base + j];

    const float rx = root[(long long)b*3 + 0] * ROOT_SCALE;
    const float ry = root[(long long)b*3 + 1] * ROOT_SCALE;
    const float rz = root[(long long)b*3 + 2] * ROOT_SCALE;

    // ---- FK chain in registers; store each joint's position directly ----
    Xform cur, sv0, sv2, loc;
#pragma unroll
    for (int j = 0; j < NJ; ++j) {
        // offsets are thread-uniform with compile-time indices -> scalar loads
        float tx = offs[j*16 + 3], ty = offs[j*16 + 7], tz = offs[j*16 + 11];
        quat_rt(q[j].x, q[j].y, q[j].z, q[j].w, tx, ty, tz, loc);
        if (j == 0) {
            cur = loc;
        } else {
            Xform nxt;
            if (j == 5 || j == 9)        compose(sv2, loc, nxt);   // parent = joint 2
            else if (j == 13 || j == 16) compose(sv0, loc, nxt);   // parent = joint 0
            else                         compose(cur, loc, nxt);   // parent = j-1
            cur = nxt;
        }
        if (j == 0) sv0 = cur;
        if (j == 2) sv2 = cur;
        float4 o;
        o.x = cur.t[0] + rx;
        o.y = cur.t[1] + ry;
        o.z = cur.t[2] + rz;
        o.w = 1.0f;                                    // M[3][3] exactly
        o4[base + j] = o;                              // fire-and-forget store
    }
}

extern "C" void kernel_launch(void* const* d_in, const int* in_sizes, int n_in,
                              void* d_out, int out_size, void* d_ws, size_t ws_size,
                              hipStream_t stream) {
    const float* root  = (const float*)d_in[0];  // (B,3)
    const float* joint = (const float*)d_in[1];  // (B,76)
    const float* offs  = (const float*)d_in[2];  // (19,4,4)
    float* out = (float*)d_out;                  // (B,19,4)
    const int batch = in_sizes[1] / (NJ * 4);
    const int grid = (batch + BLOCK - 1) / BLOCK;
    fk_kernel<<<grid, BLOCK, 0, stream>>>(root, joint, offs, out, batch);
}

// Round 3
// 157.007 us; speedup vs baseline: 1.5286x; 1.5286x over previous
//
#include <hip/hip_runtime.h>
#include <stdint.h>

#define NJ 19
#define ROOT_SCALE 200.0f
#define BLOCK 64            // 1 wave per block: no barriers, only counted waitcnts
#define ROWF 76             // floats per batch row (19 joints * 4)
#define ROWV 19             // float4s per batch row
#define SLABF (BLOCK * ROWF)   // 4864 floats per 64-row slab
#define ROOTF (BLOCK * 3)      // 192 floats of root per slab

typedef const __attribute__((address_space(1))) uint32_t* gptr_t;
typedef __attribute__((address_space(3))) uint32_t* lptr_t;

struct Xform { float r[9]; float t[3]; };

__device__ __forceinline__ void quat_rt(float w, float x, float y, float z,
                                        float tx, float ty, float tz, Xform& o) {
    float ts = 2.0f / (w*w + x*x + y*y + z*z);
    o.r[0] = 1.0f - ts*(y*y + z*z); o.r[1] = ts*(x*y - z*w);        o.r[2] = ts*(x*z + y*w);
    o.r[3] = ts*(x*y + z*w);        o.r[4] = 1.0f - ts*(x*x + z*z); o.r[5] = ts*(y*z - x*w);
    o.r[6] = ts*(x*z - y*w);        o.r[7] = ts*(y*z + x*w);        o.r[8] = 1.0f - ts*(x*x + y*y);
    o.t[0] = o.r[0]*tx + o.r[1]*ty + o.r[2]*tz;
    o.t[1] = o.r[3]*tx + o.r[4]*ty + o.r[5]*tz;
    o.t[2] = o.r[6]*tx + o.r[7]*ty + o.r[8]*tz;
}

__device__ __forceinline__ void compose(const Xform& p, const Xform& l, Xform& o) {
#pragma unroll
    for (int i = 0; i < 3; ++i) {
        o.r[i*3+0] = p.r[i*3+0]*l.r[0] + p.r[i*3+1]*l.r[3] + p.r[i*3+2]*l.r[6];
        o.r[i*3+1] = p.r[i*3+0]*l.r[1] + p.r[i*3+1]*l.r[4] + p.r[i*3+2]*l.r[7];
        o.r[i*3+2] = p.r[i*3+0]*l.r[2] + p.r[i*3+1]*l.r[5] + p.r[i*3+2]*l.r[8];
        o.t[i]     = p.r[i*3+0]*l.t[0] + p.r[i*3+1]*l.t[1] + p.r[i*3+2]*l.t[2] + p.t[i];
    }
}

// Issue one slab's load group: exactly 20 VMEM ops (19 joint + 1 root).
// LDS dest is wave-uniform base + lane*16 (linear mirror), per learn_hip m104.
__device__ __forceinline__ void issue_group(const float* __restrict__ joint,
                                            const float* __restrict__ root,
                                            long long slab, float* jb, float* rb, int tid) {
#pragma unroll
    for (int i = 0; i < ROWV; ++i) {
        __builtin_amdgcn_global_load_lds(
            (gptr_t)(joint + slab * SLABF + (long long)(i * BLOCK + tid) * 4),
            (lptr_t)(jb + i * BLOCK * 4), 16, 0, 0);
    }
    if (tid < 48) {  // 48 lanes x 16 B = 768 B of root for this slab; 1 VMEM op
        __builtin_amdgcn_global_load_lds(
            (gptr_t)(root + slab * ROOTF + tid * 4),
            (lptr_t)rb, 16, 0, 0);
    }
}

__global__ __launch_bounds__(BLOCK) void fk_pipe(
    const float* __restrict__ root, const float* __restrict__ joint,
    const float* __restrict__ offs, float* __restrict__ out, int nslab)
{
    __shared__ float jb[2][SLABF];   // 38912 B
    __shared__ float rb[2][ROOTF];   //  1536 B  -> 40448 B total -> 4 blocks/CU
    const int tid = threadIdx.x;

    // Hoist joint offsets (thread-uniform) out of the pipeline; drain their
    // loads so the in-loop vmcnt bookkeeping stays exact.
    float tx[NJ], ty[NJ], tz[NJ];
#pragma unroll
    for (int j = 0; j < NJ; ++j) {
        tx[j] = offs[j*16 + 3]; ty[j] = offs[j*16 + 7]; tz[j] = offs[j*16 + 11];
    }
    asm volatile("s_waitcnt vmcnt(0)" ::: "memory");

    long long slab = blockIdx.x;
    const int stride = gridDim.x;
    if (slab >= nslab) return;

    int p = 0;
    issue_group(joint, root, slab, jb[0], rb[0], tid);

    bool first = true;
    for (; slab < nslab; slab += stride) {
        const bool has_next = (slab + stride < (long long)nslab);
        if (has_next)
            issue_group(joint, root, slab + stride, jb[p^1], rb[p^1], tid);

        // Counted wait (T4): drain exactly the current slab's group, leave the
        // prefetch group (20) and previous stores (19) in flight. vmcnt waits
        // oldest-first, so the count is robust to scheduler interleaving.
        if (first) { if (has_next) asm volatile("s_waitcnt vmcnt(20)" ::: "memory");
                     else          asm volatile("s_waitcnt vmcnt(0)"  ::: "memory"); }
        else       { if (has_next) asm volatile("s_waitcnt vmcnt(39)" ::: "memory");
                     else          asm volatile("s_waitcnt vmcnt(19)" ::: "memory"); }
        first = false;

        // ---- per-thread FK chain from LDS row; results overwrite own row ----
        {
            float* row = &jb[p][tid * ROWF];
            const float rx = rb[p][tid*3 + 0] * ROOT_SCALE;
            const float ry = rb[p][tid*3 + 1] * ROOT_SCALE;
            const float rz = rb[p][tid*3 + 2] * ROOT_SCALE;

            Xform cur, sv0, sv2, loc;
#pragma unroll
            for (int j = 0; j < NJ; ++j) {
                float4 q = *(const float4*)(&row[j*4]);       // (w,x,y,z)
                quat_rt(q.x, q.y, q.z, q.w, tx[j], ty[j], tz[j], loc);
                if (j == 0) {
                    cur = loc;
                } else {
                    Xform nxt;
                    if (j == 5 || j == 9)        compose(sv2, loc, nxt);   // parent = 2
                    else if (j == 13 || j == 16) compose(sv0, loc, nxt);   // parent = 0
                    else                         compose(cur, loc, nxt);   // parent = j-1
                    cur = nxt;
                }
                if (j == 0) sv0 = cur;
                if (j == 2) sv2 = cur;
                float4 o;
                o.x = cur.t[0] + rx;
                o.y = cur.t[1] + ry;
                o.z = cur.t[2] + rz;
                o.w = 1.0f;                                   // M[3][3] exactly
                *(float4*)(&row[j*4]) = o;
            }
        }

        // ---- coalesced writeback: LDS is a linear mirror -> exactly 19 stores ----
        {
            const long long gb = slab * SLABF;
#pragma unroll
            for (int i = 0; i < ROWV; ++i) {
                const int v = i * BLOCK + tid;
                *(float4*)(out + gb + (long long)v * 4) = *(const float4*)(&jb[p][v*4]);
            }
        }
        p ^= 1;
    }
}

// Tail (<64 rows): trivial per-thread path, traffic negligible.
__global__ void fk_tail(const float* __restrict__ root, const float* __restrict__ joint,
                        const float* __restrict__ offs, float* __restrict__ out,
                        int start, int batch)
{
    const int b = start + threadIdx.x;
    if (b >= batch) return;
    const long long base = (long long)b * ROWF;
    const float rx = root[(long long)b*3 + 0] * ROOT_SCALE;
    const float ry = root[(long long)b*3 + 1] * ROOT_SCALE;
    const float rz = root[(long long)b*3 + 2] * ROOT_SCALE;
    Xform cur, sv0, sv2, loc;
#pragma unroll
    for (int j = 0; j < NJ; ++j) {
        float4 q = *(const float4*)(joint + base + j*4);
        quat_rt(q.x, q.y, q.z, q.w, offs[j*16+3], offs[j*16+7], offs[j*16+11], loc);
        if (j == 0) cur = loc;
        else {
            Xform nxt;
            if (j == 5 || j == 9)        compose(sv2, loc, nxt);
            else if (j == 13 || j == 16) compose(sv0, loc, nxt);
            else                         compose(cur, loc, nxt);
            cur = nxt;
        }
        if (j == 0) sv0 = cur;
        if (j == 2) sv2 = cur;
        float4 o; o.x = cur.t[0]+rx; o.y = cur.t[1]+ry; o.z = cur.t[2]+rz; o.w = 1.0f;
        *(float4*)(out + base + j*4) = o;
    }
}

extern "C" void kernel_launch(void* const* d_in, const int* in_sizes, int n_in,
                              void* d_out, int out_size, void* d_ws, size_t ws_size,
                              hipStream_t stream) {
    const float* root  = (const float*)d_in[0];  // (B,3)
    const float* joint = (const float*)d_in[1];  // (B,76)
    const float* offs  = (const float*)d_in[2];  // (19,4,4)
    float* out = (float*)d_out;                  // (B,19,4)
    const int batch = in_sizes[1] / ROWF;
    const int nslab = batch / BLOCK;
    const int tail  = batch - nslab * BLOCK;
    if (nslab > 0) {
        const int grid = nslab < 1024 ? nslab : 1024;   // 4 blocks/CU x 256 CU
        fk_pipe<<<grid, BLOCK, 0, stream>>>(root, joint, offs, out, nslab);
    }
    if (tail > 0) {
        fk_tail<<<1, BLOCK, 0, stream>>>(root, joint, offs, out, nslab * BLOCK, batch);
    }
}